// Round 1
// baseline (1198.550 us; speedup 1.0000x reference)
//
#include <hip/hip_runtime.h>

#define NN 100000
#define NE 1600000
#define FIN 128
#define HD 64
#define CO 40
#define NG 2048

// ---------------- degree ----------------
__global__ __launch_bounds__(256) void deg_kernel(const int* __restrict__ dst, float* __restrict__ deg) {
    int e = blockIdx.x * 256 + threadIdx.x;
    if (e < NE) atomicAdd(&deg[dst[e]], 1.0f);
}

__global__ __launch_bounds__(256) void disqrt_kernel(float* __restrict__ deg) {
    int i = blockIdx.x * 256 + threadIdx.x;
    if (i < NN) deg[i] = rsqrtf(deg[i] + 1.0f);
}

// ---------------- pre MLP: h = x @ pre_w + pre_b  [N,128]@[128,64] ----------------
__global__ __launch_bounds__(256) void pre_gemm(const float* __restrict__ x,
                                                const float* __restrict__ w,
                                                const float* __restrict__ b,
                                                float* __restrict__ h) {
    __shared__ float lw[FIN * HD];  // 32 KB
    for (int i = threadIdx.x; i < FIN * HD; i += 256) lw[i] = w[i];
    __syncthreads();
    int node = blockIdx.x * 4 + (threadIdx.x >> 6);
    int f = threadIdx.x & 63;
    if (node >= NN) return;
    const float* xr = x + (size_t)node * FIN;
    float acc = b[f];
#pragma unroll 8
    for (int k = 0; k < FIN; k++) acc = fmaf(xr[k], lw[k * HD + f], acc);
    h[(size_t)node * HD + f] = acc;
}

// ---------------- conv gemm: hw = hin @ W ; agg = hw * di^2 (self loop) ----------------
__global__ __launch_bounds__(256) void conv_gemm(const float* __restrict__ hin,
                                                 const float* __restrict__ w,
                                                 const float* __restrict__ di,
                                                 float* __restrict__ hw,
                                                 float* __restrict__ agg) {
    __shared__ float lw[HD * HD];  // 16 KB
    for (int i = threadIdx.x; i < HD * HD; i += 256) lw[i] = w[i];
    __syncthreads();
    int node = blockIdx.x * 4 + (threadIdx.x >> 6);
    int f = threadIdx.x & 63;
    if (node >= NN) return;
    const float* hr = hin + (size_t)node * HD;
    float acc = 0.0f;
#pragma unroll 8
    for (int k = 0; k < HD; k++) acc = fmaf(hr[k], lw[k * HD + f], acc);
    size_t idx = (size_t)node * HD + f;
    hw[idx] = acc;
    float d = di[node];
    agg[idx] = acc * d * d;
}

// ---------------- edge scatter: agg[dst] += hw[src] * di[src]*di[dst] ----------------
__global__ __launch_bounds__(256) void scatter_kernel(const int* __restrict__ src,
                                                      const int* __restrict__ dst,
                                                      const float* __restrict__ di,
                                                      const float* __restrict__ hw,
                                                      float* __restrict__ agg) {
    long long tid = (long long)blockIdx.x * 256 + threadIdx.x;
    int e = (int)(tid >> 6);
    int f = (int)(tid & 63);
    if (e >= NE) return;
    int s = src[e];
    int d = dst[e];
    float c = di[s] * di[d];
    atomicAdd(&agg[(size_t)d * HD + f], hw[(size_t)s * HD + f] * c);
}

// ---------------- bias + layernorm + relu (wave per node) ----------------
__global__ __launch_bounds__(256) void ln_relu(const float* __restrict__ agg,
                                               const float* __restrict__ cb,
                                               const float* __restrict__ g,
                                               const float* __restrict__ b,
                                               float* __restrict__ out) {
    int node = blockIdx.x * 4 + (threadIdx.x >> 6);
    int f = threadIdx.x & 63;
    if (node >= NN) return;
    size_t idx = (size_t)node * HD + f;
    float v = agg[idx] + cb[f];
    float s = v;
#pragma unroll
    for (int o = 32; o > 0; o >>= 1) s += __shfl_xor(s, o, 64);
    float mu = s * (1.0f / HD);
    float d = v - mu;
    float q = d * d;
#pragma unroll
    for (int o = 32; o > 0; o >>= 1) q += __shfl_xor(q, o, 64);
    float var = q * (1.0f / HD);
    float y = d * rsqrtf(var + 1e-5f) * g[f] + b[f];
    out[idx] = fmaxf(y, 0.0f);
}

// ---------------- layer-2 LN + relu + skip + pooled scatter ----------------
__global__ __launch_bounds__(256) void ln_relu_pool(const float* __restrict__ agg,
                                                    const float* __restrict__ cb,
                                                    const float* __restrict__ g,
                                                    const float* __restrict__ b,
                                                    const float* __restrict__ h1,
                                                    const int* __restrict__ batch,
                                                    float* __restrict__ readout) {
    int node = blockIdx.x * 4 + (threadIdx.x >> 6);
    int f = threadIdx.x & 63;
    if (node >= NN) return;
    size_t idx = (size_t)node * HD + f;
    float v = agg[idx] + cb[f];
    float s = v;
#pragma unroll
    for (int o = 32; o > 0; o >>= 1) s += __shfl_xor(s, o, 64);
    float mu = s * (1.0f / HD);
    float d = v - mu;
    float q = d * d;
#pragma unroll
    for (int o = 32; o > 0; o >>= 1) q += __shfl_xor(q, o, 64);
    float var = q * (1.0f / HD);
    float y = d * rsqrtf(var + 1e-5f) * g[f] + b[f];
    float h2 = fmaxf(y, 0.0f);
    float skip = h1[idx] + h2;
    atomicAdd(&readout[(size_t)batch[node] * HD + f], skip);
}

// ---------------- final: out = readout @ post_w + post_b  [G,64]@[64,40] ----------------
__global__ __launch_bounds__(256) void out_gemm(const float* __restrict__ r,
                                                const float* __restrict__ w,
                                                const float* __restrict__ b,
                                                float* __restrict__ out) {
    __shared__ float lw[HD * CO];  // 10 KB
    for (int i = threadIdx.x; i < HD * CO; i += 256) lw[i] = w[i];
    __syncthreads();
    int grp = blockIdx.x * 4 + (threadIdx.x >> 6);
    int c = threadIdx.x & 63;
    if (grp >= NG || c >= CO) return;
    const float* rr = r + (size_t)grp * HD;
    float acc = b[c];
#pragma unroll 8
    for (int k = 0; k < HD; k++) acc = fmaf(rr[k], lw[k * CO + c], acc);
    out[(size_t)grp * CO + c] = acc;
}

extern "C" void kernel_launch(void* const* d_in, const int* in_sizes, int n_in,
                              void* d_out, int out_size, void* d_ws, size_t ws_size,
                              hipStream_t stream) {
    const float* x      = (const float*)d_in[0];
    const int*   ei     = (const int*)d_in[1];
    const int*   batch  = (const int*)d_in[2];
    const float* pre_w  = (const float*)d_in[3];
    const float* pre_b  = (const float*)d_in[4];
    const float* c1_w   = (const float*)d_in[5];
    const float* c1_b   = (const float*)d_in[6];
    const float* n1_g   = (const float*)d_in[7];
    const float* n1_b   = (const float*)d_in[8];
    const float* c2_w   = (const float*)d_in[9];
    const float* c2_b   = (const float*)d_in[10];
    const float* n2_g   = (const float*)d_in[11];
    const float* n2_b   = (const float*)d_in[12];
    const float* post_w = (const float*)d_in[13];
    const float* post_b = (const float*)d_in[14];

    const int* src = ei;
    const int* dst = ei + NE;

    float* ws      = (float*)d_ws;
    float* di      = ws;                        // N
    float* bufA    = di + NN;                   // N*64 : h, later agg2
    float* bufB    = bufA + (size_t)NN * HD;    // N*64 : hw1, hw2
    float* bufC    = bufB + (size_t)NN * HD;    // N*64 : agg1 -> h1
    float* readout = bufC + (size_t)NN * HD;    // G*64

    hipMemsetAsync(di, 0, NN * sizeof(float), stream);
    hipMemsetAsync(readout, 0, (size_t)NG * HD * sizeof(float), stream);

    deg_kernel<<<(NE + 255) / 256, 256, 0, stream>>>(dst, di);
    disqrt_kernel<<<(NN + 255) / 256, 256, 0, stream>>>(di);

    pre_gemm<<<(NN + 3) / 4, 256, 0, stream>>>(x, pre_w, pre_b, bufA);

    // layer 1
    conv_gemm<<<(NN + 3) / 4, 256, 0, stream>>>(bufA, c1_w, di, bufB, bufC);
    scatter_kernel<<<(int)(((long long)NE * 64 + 255) / 256), 256, 0, stream>>>(src, dst, di, bufB, bufC);
    ln_relu<<<(NN + 3) / 4, 256, 0, stream>>>(bufC, c1_b, n1_g, n1_b, bufC);  // in-place -> h1

    // layer 2
    conv_gemm<<<(NN + 3) / 4, 256, 0, stream>>>(bufC, c2_w, di, bufB, bufA);
    scatter_kernel<<<(int)(((long long)NE * 64 + 255) / 256), 256, 0, stream>>>(src, dst, di, bufB, bufA);
    ln_relu_pool<<<(NN + 3) / 4, 256, 0, stream>>>(bufA, c2_b, n2_g, n2_b, bufC, batch, readout);

    out_gemm<<<(NG + 3) / 4, 256, 0, stream>>>(readout, post_w, post_b, (float*)d_out);
}

// Round 2
// 743.340 us; speedup vs baseline: 1.6124x; 1.6124x over previous
//
#include <hip/hip_runtime.h>

#define NN 100000
#define NE 1600000
#define FIN 128
#define HD 64
#define CO 40
#define NG 2048
#define NBLK1 98   // ceil(100000/1024)

// ---------------- histogram of dst (in-degree) ----------------
__global__ __launch_bounds__(256) void hist_kernel(const int* __restrict__ dst, int* __restrict__ degi) {
    int e = blockIdx.x * 256 + threadIdx.x;
    if (e < NE) atomicAdd(&degi[dst[e]], 1);
}

// ---------------- scan stage 1: per-block (1024 elems) exclusive scan ----------------
__global__ __launch_bounds__(256) void scan1_kernel(const int* __restrict__ degi,
                                                    int* __restrict__ offs,
                                                    int* __restrict__ bsums) {
    __shared__ int s[256];
    int t = threadIdx.x;
    int base = blockIdx.x * 1024 + t * 4;
    int v0 = 0, v1 = 0, v2 = 0, v3 = 0;
    if (base + 0 < NN) v0 = degi[base + 0];
    if (base + 1 < NN) v1 = degi[base + 1];
    if (base + 2 < NN) v2 = degi[base + 2];
    if (base + 3 < NN) v3 = degi[base + 3];
    int sum = v0 + v1 + v2 + v3;
    s[t] = sum;
    __syncthreads();
    for (int off = 1; off < 256; off <<= 1) {
        int x = (t >= off) ? s[t - off] : 0;
        __syncthreads();
        s[t] += x;
        __syncthreads();
    }
    int excl = s[t] - sum;
    if (t == 255) bsums[blockIdx.x] = s[255];
    int run = excl;
    if (base + 0 < NN) { offs[base + 0] = run; run += v0; }
    if (base + 1 < NN) { offs[base + 1] = run; run += v1; }
    if (base + 2 < NN) { offs[base + 2] = run; run += v2; }
    if (base + 3 < NN) { offs[base + 3] = run; run += v3; }
}

// ---------------- scan stage 2: scan the 98 block sums (inclusive) ----------------
__global__ __launch_bounds__(128) void scan2_kernel(int* __restrict__ bsums) {
    __shared__ int s[128];
    int t = threadIdx.x;
    s[t] = (t < NBLK1) ? bsums[t] : 0;
    __syncthreads();
    for (int off = 1; off < 128; off <<= 1) {
        int x = (t >= off) ? s[t - off] : 0;
        __syncthreads();
        s[t] += x;
        __syncthreads();
    }
    if (t < NBLK1) bsums[t] = s[t];
}

// ---------------- scan stage 3: add block prefix; emit cursor copy + deg_isqrt ----------------
__global__ __launch_bounds__(256) void scan3_kernel(const int* __restrict__ degi,
                                                    int* __restrict__ offs,
                                                    const int* __restrict__ bsums,
                                                    int* __restrict__ cursor,
                                                    float* __restrict__ di) {
    int i = blockIdx.x * 256 + threadIdx.x;
    if (i >= NN) return;
    int b = i >> 10;
    int add = (b > 0) ? bsums[b - 1] : 0;
    int o = offs[i] + add;
    offs[i] = o;
    cursor[i] = o;
    di[i] = rsqrtf((float)degi[i] + 1.0f);
}

// ---------------- build dst-sorted src list ----------------
__global__ __launch_bounds__(256) void build_kernel(const int* __restrict__ src,
                                                    const int* __restrict__ dst,
                                                    int* __restrict__ cursor,
                                                    int* __restrict__ ssrc) {
    int e = blockIdx.x * 256 + threadIdx.x;
    if (e >= NE) return;
    int d = dst[e];
    int pos = atomicAdd(&cursor[d], 1);
    ssrc[pos] = src[e];
}

// ---------------- W_eff = pre_w @ c1_w ; b_eff = pre_b @ c1_w ----------------
__global__ __launch_bounds__(256) void weff_kernel(const float* __restrict__ pre_w,
                                                   const float* __restrict__ pre_b,
                                                   const float* __restrict__ c1_w,
                                                   float* __restrict__ weff,
                                                   float* __restrict__ beff) {
    if (blockIdx.x < 32) {
        int o = blockIdx.x * 256 + threadIdx.x;  // o in [0, 8192)
        int r = o >> 6, c = o & 63;
        float acc = 0.0f;
#pragma unroll 8
        for (int k = 0; k < HD; k++) acc = fmaf(pre_w[r * HD + k], c1_w[k * HD + c], acc);
        weff[o] = acc;
    } else {
        int c = threadIdx.x;
        if (c < HD) {
            float acc = 0.0f;
#pragma unroll 8
            for (int k = 0; k < HD; k++) acc = fmaf(pre_b[k], c1_w[k * HD + c], acc);
            beff[c] = acc;
        }
    }
}

// ---------------- hw1 = x @ W_eff + b_eff  [N,128]@[128,64] ----------------
__global__ __launch_bounds__(256) void gemm1_kernel(const float* __restrict__ x,
                                                    const float* __restrict__ w,
                                                    const float* __restrict__ b,
                                                    float* __restrict__ hw) {
    __shared__ float lw[FIN * HD];  // 32 KB
    for (int i = threadIdx.x; i < FIN * HD; i += 256) lw[i] = w[i];
    __syncthreads();
    int node = blockIdx.x * 4 + (threadIdx.x >> 6);
    int f = threadIdx.x & 63;
    if (node >= NN) return;
    const float* xr = x + (size_t)node * FIN;
    float acc = b[f];
#pragma unroll 8
    for (int k = 0; k < FIN; k++) acc = fmaf(xr[k], lw[k * HD + f], acc);
    hw[(size_t)node * HD + f] = acc;
}

// ---------------- hw2 = h1 @ c2_w  [N,64]@[64,64] ----------------
__global__ __launch_bounds__(256) void conv_gemm(const float* __restrict__ hin,
                                                 const float* __restrict__ w,
                                                 float* __restrict__ hw) {
    __shared__ float lw[HD * HD];  // 16 KB
    for (int i = threadIdx.x; i < HD * HD; i += 256) lw[i] = w[i];
    __syncthreads();
    int node = blockIdx.x * 4 + (threadIdx.x >> 6);
    int f = threadIdx.x & 63;
    if (node >= NN) return;
    const float* hr = hin + (size_t)node * HD;
    float acc = 0.0f;
#pragma unroll 8
    for (int k = 0; k < HD; k++) acc = fmaf(hr[k], lw[k * HD + f], acc);
    hw[(size_t)node * HD + f] = acc;
}

// ---------------- layer-1 gather + bias + LN + ReLU (wave per node) ----------------
__global__ __launch_bounds__(256) void gather_ln(const int* __restrict__ offs,
                                                 const int* __restrict__ ssrc,
                                                 const float* __restrict__ di,
                                                 const float* __restrict__ hw,
                                                 const float* __restrict__ cb,
                                                 const float* __restrict__ g,
                                                 const float* __restrict__ bb,
                                                 float* __restrict__ out) {
    int node = blockIdx.x * 4 + (threadIdx.x >> 6);
    int f = threadIdx.x & 63;
    int beg = offs[node];
    int end = (node + 1 < NN) ? offs[node + 1] : NE;
    float dn = di[node];
    float acc = hw[(size_t)node * HD + f] * dn * dn;
    int i = beg;
    while (i < end) {
        int cnt = end - i;
        if (cnt > 64) cnt = 64;
        int sl = 0;
        float dl = 0.0f;
        if (f < cnt) { sl = ssrc[i + f]; dl = di[sl]; }
#pragma unroll 4
        for (int j = 0; j < cnt; j++) {
            int s = __shfl(sl, j, 64);
            float c = __shfl(dl, j, 64) * dn;
            acc = fmaf(hw[(size_t)s * HD + f], c, acc);
        }
        i += cnt;
    }
    float v = acc + cb[f];
    float su = v;
#pragma unroll
    for (int o = 32; o > 0; o >>= 1) su += __shfl_xor(su, o, 64);
    float mu = su * (1.0f / HD);
    float d = v - mu;
    float q = d * d;
#pragma unroll
    for (int o = 32; o > 0; o >>= 1) q += __shfl_xor(q, o, 64);
    float var = q * (1.0f / HD);
    float y = d * rsqrtf(var + 1e-5f) * g[f] + bb[f];
    out[(size_t)node * HD + f] = fmaxf(y, 0.0f);
}

// ---------------- layer-2 gather + LN + ReLU + skip + pooled scatter ----------------
__global__ __launch_bounds__(256) void gather_ln_pool(const int* __restrict__ offs,
                                                      const int* __restrict__ ssrc,
                                                      const float* __restrict__ di,
                                                      const float* __restrict__ hw,
                                                      const float* __restrict__ cb,
                                                      const float* __restrict__ g,
                                                      const float* __restrict__ bb,
                                                      const float* __restrict__ h1,
                                                      const int* __restrict__ batch,
                                                      float* __restrict__ readout) {
    __shared__ float ls[4][HD];
    __shared__ int lb[4];
    int w = threadIdx.x >> 6;
    int node = blockIdx.x * 4 + w;   // NN divisible by 4: always valid
    int f = threadIdx.x & 63;
    int beg = offs[node];
    int end = (node + 1 < NN) ? offs[node + 1] : NE;
    float dn = di[node];
    size_t idx = (size_t)node * HD + f;
    float acc = hw[idx] * dn * dn;
    int i = beg;
    while (i < end) {
        int cnt = end - i;
        if (cnt > 64) cnt = 64;
        int sl = 0;
        float dl = 0.0f;
        if (f < cnt) { sl = ssrc[i + f]; dl = di[sl]; }
#pragma unroll 4
        for (int j = 0; j < cnt; j++) {
            int s = __shfl(sl, j, 64);
            float c = __shfl(dl, j, 64) * dn;
            acc = fmaf(hw[(size_t)s * HD + f], c, acc);
        }
        i += cnt;
    }
    float v = acc + cb[f];
    float su = v;
#pragma unroll
    for (int o = 32; o > 0; o >>= 1) su += __shfl_xor(su, o, 64);
    float mu = su * (1.0f / HD);
    float d = v - mu;
    float q = d * d;
#pragma unroll
    for (int o = 32; o > 0; o >>= 1) q += __shfl_xor(q, o, 64);
    float var = q * (1.0f / HD);
    float y = d * rsqrtf(var + 1e-5f) * g[f] + bb[f];
    float h2 = fmaxf(y, 0.0f);
    float skip = h1[idx] + h2;
    int bn = batch[node];
    ls[w][f] = skip;
    if (f == 0) lb[w] = bn;
    __syncthreads();
    bool same = (lb[0] == lb[1]) && (lb[1] == lb[2]) && (lb[2] == lb[3]);
    if (same) {
        if (w == 0) {
            float s4 = ls[0][f] + ls[1][f] + ls[2][f] + ls[3][f];
            atomicAdd(&readout[(size_t)lb[0] * HD + f], s4);
        }
    } else {
        atomicAdd(&readout[(size_t)bn * HD + f], skip);
    }
}

// ---------------- final: out = readout @ post_w + post_b  [G,64]@[64,40] ----------------
__global__ __launch_bounds__(256) void out_gemm(const float* __restrict__ r,
                                                const float* __restrict__ w,
                                                const float* __restrict__ b,
                                                float* __restrict__ out) {
    __shared__ float lw[HD * CO];
    for (int i = threadIdx.x; i < HD * CO; i += 256) lw[i] = w[i];
    __syncthreads();
    int grp = blockIdx.x * 4 + (threadIdx.x >> 6);
    int c = threadIdx.x & 63;
    if (grp >= NG || c >= CO) return;
    const float* rr = r + (size_t)grp * HD;
    float acc = b[c];
#pragma unroll 8
    for (int k = 0; k < HD; k++) acc = fmaf(rr[k], lw[k * CO + c], acc);
    out[(size_t)grp * CO + c] = acc;
}

extern "C" void kernel_launch(void* const* d_in, const int* in_sizes, int n_in,
                              void* d_out, int out_size, void* d_ws, size_t ws_size,
                              hipStream_t stream) {
    const float* x      = (const float*)d_in[0];
    const int*   ei     = (const int*)d_in[1];
    const int*   batch  = (const int*)d_in[2];
    const float* pre_w  = (const float*)d_in[3];
    const float* pre_b  = (const float*)d_in[4];
    const float* c1_w   = (const float*)d_in[5];
    const float* c1_b   = (const float*)d_in[6];
    const float* n1_g   = (const float*)d_in[7];
    const float* n1_b   = (const float*)d_in[8];
    const float* c2_w   = (const float*)d_in[9];
    const float* c2_b   = (const float*)d_in[10];
    const float* n2_g   = (const float*)d_in[11];
    const float* n2_b   = (const float*)d_in[12];
    const float* post_w = (const float*)d_in[13];
    const float* post_b = (const float*)d_in[14];

    const int* src = ei;
    const int* dst = ei + NE;

    char* p = (char*)d_ws;
    int*   degi    = (int*)p;                 p += (size_t)NN * 4;
    int*   offs    = (int*)p;                 p += (size_t)NN * 4;
    int*   cursor  = (int*)p;                 p += (size_t)NN * 4;
    int*   bsums   = (int*)p;                 p += 512;
    float* di      = (float*)p;               p += (size_t)NN * 4;
    float* weff    = (float*)p;               p += (size_t)FIN * HD * 4;
    float* beff    = (float*)p;               p += (size_t)HD * 4;
    int*   ssrc    = (int*)p;                 p += (size_t)NE * 4;
    float* hwbuf   = (float*)p;               p += (size_t)NN * HD * 4;
    float* h1      = (float*)p;               p += (size_t)NN * HD * 4;
    float* readout = (float*)p;               p += (size_t)NG * HD * 4;

    hipMemsetAsync(degi, 0, (size_t)NN * 4, stream);
    hipMemsetAsync(readout, 0, (size_t)NG * HD * 4, stream);

    // CSR build (shared by both layers)
    hist_kernel<<<(NE + 255) / 256, 256, 0, stream>>>(dst, degi);
    scan1_kernel<<<NBLK1, 256, 0, stream>>>(degi, offs, bsums);
    scan2_kernel<<<1, 128, 0, stream>>>(bsums);
    scan3_kernel<<<(NN + 255) / 256, 256, 0, stream>>>(degi, offs, bsums, cursor, di);
    build_kernel<<<(NE + 255) / 256, 256, 0, stream>>>(src, dst, cursor, ssrc);

    // Folded pre-MLP weights
    weff_kernel<<<33, 256, 0, stream>>>(pre_w, pre_b, c1_w, weff, beff);

    // layer 1
    gemm1_kernel<<<NN / 4, 256, 0, stream>>>(x, weff, beff, hwbuf);
    gather_ln<<<NN / 4, 256, 0, stream>>>(offs, ssrc, di, hwbuf, c1_b, n1_g, n1_b, h1);

    // layer 2
    conv_gemm<<<NN / 4, 256, 0, stream>>>(h1, c2_w, hwbuf);
    gather_ln_pool<<<NN / 4, 256, 0, stream>>>(offs, ssrc, di, hwbuf, c2_b, n2_g, n2_b, h1, batch, readout);

    out_gemm<<<(NG + 3) / 4, 256, 0, stream>>>(readout, post_w, post_b, (float*)d_out);
}

// Round 4
// 618.281 us; speedup vs baseline: 1.9385x; 1.2023x over previous
//
#include <hip/hip_runtime.h>

#define NN 100000
#define NE 1600000
#define FIN 128
#define HD 64
#define CO 40
#define NG 2048
#define NBLK1 98   // ceil(100000/1024)

// ---------------- histogram of dst (in-degree) ----------------
__global__ __launch_bounds__(256) void hist_kernel(const int* __restrict__ dst, int* __restrict__ degi) {
    int e = blockIdx.x * 256 + threadIdx.x;
    if (e < NE) atomicAdd(&degi[dst[e]], 1);
}

// ---------------- scan stage 1: per-block (1024 elems) exclusive scan ----------------
__global__ __launch_bounds__(256) void scan1_kernel(const int* __restrict__ degi,
                                                    int* __restrict__ offs,
                                                    int* __restrict__ bsums) {
    __shared__ int s[256];
    int t = threadIdx.x;
    int base = blockIdx.x * 1024 + t * 4;
    int v0 = 0, v1 = 0, v2 = 0, v3 = 0;
    if (base + 0 < NN) v0 = degi[base + 0];
    if (base + 1 < NN) v1 = degi[base + 1];
    if (base + 2 < NN) v2 = degi[base + 2];
    if (base + 3 < NN) v3 = degi[base + 3];
    int sum = v0 + v1 + v2 + v3;
    s[t] = sum;
    __syncthreads();
    for (int off = 1; off < 256; off <<= 1) {
        int x = (t >= off) ? s[t - off] : 0;
        __syncthreads();
        s[t] += x;
        __syncthreads();
    }
    int excl = s[t] - sum;
    if (t == 255) bsums[blockIdx.x] = s[255];
    int run = excl;
    if (base + 0 < NN) { offs[base + 0] = run; run += v0; }
    if (base + 1 < NN) { offs[base + 1] = run; run += v1; }
    if (base + 2 < NN) { offs[base + 2] = run; run += v2; }
    if (base + 3 < NN) { offs[base + 3] = run; run += v3; }
}

// ---------------- scan stage 2: scan the 98 block sums (inclusive) ----------------
__global__ __launch_bounds__(128) void scan2_kernel(int* __restrict__ bsums) {
    __shared__ int s[128];
    int t = threadIdx.x;
    s[t] = (t < NBLK1) ? bsums[t] : 0;
    __syncthreads();
    for (int off = 1; off < 128; off <<= 1) {
        int x = (t >= off) ? s[t - off] : 0;
        __syncthreads();
        s[t] += x;
        __syncthreads();
    }
    if (t < NBLK1) bsums[t] = s[t];
}

// ---------------- scan stage 3: add block prefix; emit cursor copy + deg_isqrt ----------------
__global__ __launch_bounds__(256) void scan3_kernel(const int* __restrict__ degi,
                                                    int* __restrict__ offs,
                                                    const int* __restrict__ bsums,
                                                    int* __restrict__ cursor,
                                                    float* __restrict__ di) {
    int i = blockIdx.x * 256 + threadIdx.x;
    if (i >= NN) return;
    int b = i >> 10;
    int add = (b > 0) ? bsums[b - 1] : 0;
    int o = offs[i] + add;
    offs[i] = o;
    cursor[i] = o;
    di[i] = rsqrtf((float)degi[i] + 1.0f);
}

// ---------------- build dst-sorted src list ----------------
__global__ __launch_bounds__(256) void build_kernel(const int* __restrict__ src,
                                                    const int* __restrict__ dst,
                                                    int* __restrict__ cursor,
                                                    int* __restrict__ ssrc) {
    int e = blockIdx.x * 256 + threadIdx.x;
    if (e >= NE) return;
    int d = dst[e];
    int pos = atomicAdd(&cursor[d], 1);
    ssrc[pos] = src[e];
}

// ---------------- W_eff = pre_w @ c1_w ; b_eff = pre_b @ c1_w ----------------
__global__ __launch_bounds__(256) void weff_kernel(const float* __restrict__ pre_w,
                                                   const float* __restrict__ pre_b,
                                                   const float* __restrict__ c1_w,
                                                   float* __restrict__ weff,
                                                   float* __restrict__ beff) {
    if (blockIdx.x < 32) {
        int o = blockIdx.x * 256 + threadIdx.x;  // o in [0, 8192)
        int r = o >> 6, c = o & 63;
        float acc = 0.0f;
#pragma unroll 8
        for (int k = 0; k < HD; k++) acc = fmaf(pre_w[r * HD + k], c1_w[k * HD + c], acc);
        weff[o] = acc;
    } else {
        int c = threadIdx.x;
        if (c < HD) {
            float acc = 0.0f;
#pragma unroll 8
            for (int k = 0; k < HD; k++) acc = fmaf(pre_b[k], c1_w[k * HD + c], acc);
            beff[c] = acc;
        }
    }
}

// ---------------- hws = (x @ W_eff + b_eff) * di  [N,128]@[128,64], persistent ----------------
__global__ __launch_bounds__(256) void gemm1_kernel(const float* __restrict__ x,
                                                    const float* __restrict__ w,
                                                    const float* __restrict__ b,
                                                    const float* __restrict__ di,
                                                    float* __restrict__ hws) {
    __shared__ float lw[FIN * HD];  // 32 KB
    for (int i = threadIdx.x; i < FIN * HD; i += 256) lw[i] = w[i];
    __syncthreads();
    int wv = threadIdx.x >> 6;
    int f = threadIdx.x & 63;
    float bf = b[f];
    for (int base = blockIdx.x * 8; base < NN; base += gridDim.x * 8) {
        int n0 = base + wv * 2, n1 = n0 + 1;   // NN % 8 == 0 -> always valid
        const float4* x0 = (const float4*)(x + (size_t)n0 * FIN);
        const float4* x1 = (const float4*)(x + (size_t)n1 * FIN);
        float acc0 = bf, acc1 = bf;
#pragma unroll 4
        for (int k4 = 0; k4 < FIN / 4; k4++) {
            float4 a0 = x0[k4], a1 = x1[k4];
            float w0 = lw[(k4 * 4 + 0) * HD + f];
            float w1 = lw[(k4 * 4 + 1) * HD + f];
            float w2 = lw[(k4 * 4 + 2) * HD + f];
            float w3 = lw[(k4 * 4 + 3) * HD + f];
            acc0 = fmaf(a0.x, w0, acc0); acc1 = fmaf(a1.x, w0, acc1);
            acc0 = fmaf(a0.y, w1, acc0); acc1 = fmaf(a1.y, w1, acc1);
            acc0 = fmaf(a0.z, w2, acc0); acc1 = fmaf(a1.z, w2, acc1);
            acc0 = fmaf(a0.w, w3, acc0); acc1 = fmaf(a1.w, w3, acc1);
        }
        hws[(size_t)n0 * HD + f] = acc0 * di[n0];
        hws[(size_t)n1 * HD + f] = acc1 * di[n1];
    }
}

// ---------------- hws2 = (h1 @ c2_w) * di  [N,64]@[64,64], persistent ----------------
__global__ __launch_bounds__(256) void conv_gemm(const float* __restrict__ hin,
                                                 const float* __restrict__ w,
                                                 const float* __restrict__ di,
                                                 float* __restrict__ hws) {
    __shared__ float lw[HD * HD];  // 16 KB
    for (int i = threadIdx.x; i < HD * HD; i += 256) lw[i] = w[i];
    __syncthreads();
    int wv = threadIdx.x >> 6;
    int f = threadIdx.x & 63;
    for (int base = blockIdx.x * 8; base < NN; base += gridDim.x * 8) {
        int n0 = base + wv * 2, n1 = n0 + 1;
        const float4* x0 = (const float4*)(hin + (size_t)n0 * HD);
        const float4* x1 = (const float4*)(hin + (size_t)n1 * HD);
        float acc0 = 0.0f, acc1 = 0.0f;
#pragma unroll 4
        for (int k4 = 0; k4 < HD / 4; k4++) {
            float4 a0 = x0[k4], a1 = x1[k4];
            float w0 = lw[(k4 * 4 + 0) * HD + f];
            float w1 = lw[(k4 * 4 + 1) * HD + f];
            float w2 = lw[(k4 * 4 + 2) * HD + f];
            float w3 = lw[(k4 * 4 + 3) * HD + f];
            acc0 = fmaf(a0.x, w0, acc0); acc1 = fmaf(a1.x, w0, acc1);
            acc0 = fmaf(a0.y, w1, acc0); acc1 = fmaf(a1.y, w1, acc1);
            acc0 = fmaf(a0.z, w2, acc0); acc1 = fmaf(a1.z, w2, acc1);
            acc0 = fmaf(a0.w, w3, acc0); acc1 = fmaf(a1.w, w3, acc1);
        }
        hws[(size_t)n0 * HD + f] = acc0 * di[n0];
        hws[(size_t)n1 * HD + f] = acc1 * di[n1];
    }
}

// =====================================================================
// Gather core: wave per node, float4 lanes (16 lanes/row, 4 rows/load).
// NOTE: every __shfl is executed by ALL 64 lanes (ds_bpermute requires the
// SOURCE lane to be active to push its value); only accumulation is guarded.
// =====================================================================
__device__ __forceinline__ float4 gather_quad(const int* __restrict__ offs,
                                              const int* __restrict__ ssrc,
                                              const float* __restrict__ hws,
                                              int node, int lane, int fp, int rsub) {
    int beg = offs[node];
    int end = (node + 1 < NN) ? offs[node + 1] : NE;
    float4 acc;
    if (rsub == 0) {  // self term, counted once across the rsub groups
        acc = ((const float4*)(hws + (size_t)node * HD))[fp];
    } else {
        acc.x = 0.0f; acc.y = 0.0f; acc.z = 0.0f; acc.w = 0.0f;
    }
    int i = beg;
    while (i < end) {
        int cnt = end - i;
        if (cnt > 64) cnt = 64;
        int sl = (lane < cnt) ? ssrc[i + lane] : 0;
        int j = 0;
        for (; j + 4 <= cnt; j += 4) {
            int s = __shfl(sl, j + rsub, 64);   // non-divergent: all lanes active
            float4 v = ((const float4*)(hws + (size_t)s * HD))[fp];
            acc.x += v.x; acc.y += v.y; acc.z += v.z; acc.w += v.w;
        }
        if (j < cnt) {  // tail 1..3 rows
            int jr = j + rsub;
            int s = __shfl(sl, (jr < cnt) ? jr : 0, 64);  // ALL lanes execute the bpermute
            if (jr < cnt) {
                float4 v = ((const float4*)(hws + (size_t)s * HD))[fp];
                acc.x += v.x; acc.y += v.y; acc.z += v.z; acc.w += v.w;
            }
        }
        i += cnt;
    }
    // combine the 4 rsub groups
    acc.x += __shfl_xor(acc.x, 16, 64); acc.y += __shfl_xor(acc.y, 16, 64);
    acc.z += __shfl_xor(acc.z, 16, 64); acc.w += __shfl_xor(acc.w, 16, 64);
    acc.x += __shfl_xor(acc.x, 32, 64); acc.y += __shfl_xor(acc.y, 32, 64);
    acc.z += __shfl_xor(acc.z, 32, 64); acc.w += __shfl_xor(acc.w, 32, 64);
    return acc;
}

__device__ __forceinline__ float4 ln_quad(float4 v, int lane, int fp,
                                          const float* __restrict__ g,
                                          const float* __restrict__ bb) {
    float su = v.x + v.y + v.z + v.w;
#pragma unroll
    for (int o = 1; o < 16; o <<= 1) su += __shfl_xor(su, o, 64);
    float mu = su * (1.0f / HD);
    float dx = v.x - mu, dy = v.y - mu, dz = v.z - mu, dw = v.w - mu;
    float q = dx * dx + dy * dy + dz * dz + dw * dw;
#pragma unroll
    for (int o = 1; o < 16; o <<= 1) q += __shfl_xor(q, o, 64);
    float rstd = rsqrtf(q * (1.0f / HD) + 1e-5f);
    float4 g4 = ((const float4*)g)[fp];
    float4 b4 = ((const float4*)bb)[fp];
    float4 y;
    y.x = fmaxf(dx * rstd * g4.x + b4.x, 0.0f);
    y.y = fmaxf(dy * rstd * g4.y + b4.y, 0.0f);
    y.z = fmaxf(dz * rstd * g4.z + b4.z, 0.0f);
    y.w = fmaxf(dw * rstd * g4.w + b4.w, 0.0f);
    return y;
}

// ---------------- layer-1 gather + bias + LN + ReLU ----------------
__global__ __launch_bounds__(256) void gather_ln(const int* __restrict__ offs,
                                                 const int* __restrict__ ssrc,
                                                 const float* __restrict__ di,
                                                 const float* __restrict__ hws,
                                                 const float* __restrict__ cb,
                                                 const float* __restrict__ g,
                                                 const float* __restrict__ bb,
                                                 float* __restrict__ out) {
    int wv = threadIdx.x >> 6;
    int lane = threadIdx.x & 63;
    int fp = lane & 15, rsub = lane >> 4;
    int node = blockIdx.x * 4 + wv;      // NN % 4 == 0
    float4 acc = gather_quad(offs, ssrc, hws, node, lane, fp, rsub);
    float dn = di[node];
    float4 cb4 = ((const float4*)cb)[fp];
    float4 v;
    v.x = acc.x * dn + cb4.x; v.y = acc.y * dn + cb4.y;
    v.z = acc.z * dn + cb4.z; v.w = acc.w * dn + cb4.w;
    float4 y = ln_quad(v, lane, fp, g, bb);
    if (rsub == 0) ((float4*)(out + (size_t)node * HD))[fp] = y;
}

// ---------------- layer-2 gather + LN + ReLU + skip + pooled scatter ----------------
__global__ __launch_bounds__(256) void gather_ln_pool(const int* __restrict__ offs,
                                                      const int* __restrict__ ssrc,
                                                      const float* __restrict__ di,
                                                      const float* __restrict__ hws,
                                                      const float* __restrict__ cb,
                                                      const float* __restrict__ g,
                                                      const float* __restrict__ bb,
                                                      const float* __restrict__ h1,
                                                      const int* __restrict__ batch,
                                                      float* __restrict__ readout) {
    __shared__ float ls[4][HD];
    __shared__ int lb[4];
    int wv = threadIdx.x >> 6;
    int lane = threadIdx.x & 63;
    int fp = lane & 15, rsub = lane >> 4;
    int node = blockIdx.x * 4 + wv;
    float4 acc = gather_quad(offs, ssrc, hws, node, lane, fp, rsub);
    float dn = di[node];
    float4 cb4 = ((const float4*)cb)[fp];
    float4 v;
    v.x = acc.x * dn + cb4.x; v.y = acc.y * dn + cb4.y;
    v.z = acc.z * dn + cb4.z; v.w = acc.w * dn + cb4.w;
    float4 y = ln_quad(v, lane, fp, g, bb);
    if (rsub == 0) {
        float4 h4 = ((const float4*)(h1 + (size_t)node * HD))[fp];
        float4 sk;
        sk.x = y.x + h4.x; sk.y = y.y + h4.y; sk.z = y.z + h4.z; sk.w = y.w + h4.w;
        ((float4*)ls[wv])[fp] = sk;
    }
    if (lane == 0) lb[wv] = batch[node];
    __syncthreads();
    int f = lane;
    bool same = (lb[0] == lb[1]) && (lb[1] == lb[2]) && (lb[2] == lb[3]);
    if (same) {
        if (wv == 0) {
            float s4 = ls[0][f] + ls[1][f] + ls[2][f] + ls[3][f];
            atomicAdd(&readout[(size_t)lb[0] * HD + f], s4);
        }
    } else {
        atomicAdd(&readout[(size_t)lb[wv] * HD + f], ls[wv][f]);
    }
}

// ---------------- final: out = readout @ post_w + post_b  [G,64]@[64,40] ----------------
__global__ __launch_bounds__(256) void out_gemm(const float* __restrict__ r,
                                                const float* __restrict__ w,
                                                const float* __restrict__ b,
                                                float* __restrict__ out) {
    __shared__ float lw[HD * CO];
    for (int i = threadIdx.x; i < HD * CO; i += 256) lw[i] = w[i];
    __syncthreads();
    int grp = blockIdx.x * 4 + (threadIdx.x >> 6);
    int c = threadIdx.x & 63;
    if (grp >= NG || c >= CO) return;
    const float* rr = r + (size_t)grp * HD;
    float acc = b[c];
#pragma unroll 8
    for (int k = 0; k < HD; k++) acc = fmaf(rr[k], lw[k * CO + c], acc);
    out[(size_t)grp * CO + c] = acc;
}

extern "C" void kernel_launch(void* const* d_in, const int* in_sizes, int n_in,
                              void* d_out, int out_size, void* d_ws, size_t ws_size,
                              hipStream_t stream) {
    const float* x      = (const float*)d_in[0];
    const int*   ei     = (const int*)d_in[1];
    const int*   batch  = (const int*)d_in[2];
    const float* pre_w  = (const float*)d_in[3];
    const float* pre_b  = (const float*)d_in[4];
    const float* c1_w   = (const float*)d_in[5];
    const float* c1_b   = (const float*)d_in[6];
    const float* n1_g   = (const float*)d_in[7];
    const float* n1_b   = (const float*)d_in[8];
    const float* c2_w   = (const float*)d_in[9];
    const float* c2_b   = (const float*)d_in[10];
    const float* n2_g   = (const float*)d_in[11];
    const float* n2_b   = (const float*)d_in[12];
    const float* post_w = (const float*)d_in[13];
    const float* post_b = (const float*)d_in[14];

    const int* src = ei;
    const int* dst = ei + NE;

    char* p = (char*)d_ws;
    int*   degi    = (int*)p;                 p += (size_t)NN * 4;
    int*   offs    = (int*)p;                 p += (size_t)NN * 4;
    int*   cursor  = (int*)p;                 p += (size_t)NN * 4;
    int*   bsums   = (int*)p;                 p += 512;
    float* di      = (float*)p;               p += (size_t)NN * 4;
    float* weff    = (float*)p;               p += (size_t)FIN * HD * 4;
    float* beff    = (float*)p;               p += (size_t)HD * 4;
    int*   ssrc    = (int*)p;                 p += (size_t)NE * 4;
    float* hws     = (float*)p;               p += (size_t)NN * HD * 4;
    float* h1      = (float*)p;               p += (size_t)NN * HD * 4;
    float* readout = (float*)p;               p += (size_t)NG * HD * 4;

    hipMemsetAsync(degi, 0, (size_t)NN * 4, stream);
    hipMemsetAsync(readout, 0, (size_t)NG * HD * 4, stream);

    // CSR build (shared by both layers)
    hist_kernel<<<(NE + 255) / 256, 256, 0, stream>>>(dst, degi);
    scan1_kernel<<<NBLK1, 256, 0, stream>>>(degi, offs, bsums);
    scan2_kernel<<<1, 128, 0, stream>>>(bsums);
    scan3_kernel<<<(NN + 255) / 256, 256, 0, stream>>>(degi, offs, bsums, cursor, di);
    build_kernel<<<(NE + 255) / 256, 256, 0, stream>>>(src, dst, cursor, ssrc);

    // Folded pre-MLP weights
    weff_kernel<<<33, 256, 0, stream>>>(pre_w, pre_b, c1_w, weff, beff);

    // layer 1
    gemm1_kernel<<<1280, 256, 0, stream>>>(x, weff, beff, di, hws);
    gather_ln<<<NN / 4, 256, 0, stream>>>(offs, ssrc, di, hws, c1_b, n1_g, n1_b, h1);

    // layer 2
    conv_gemm<<<2048, 256, 0, stream>>>(h1, c2_w, di, hws);
    gather_ln_pool<<<NN / 4, 256, 0, stream>>>(offs, ssrc, di, hws, c2_b, n2_g, n2_b, h1, batch, readout);

    out_gemm<<<(NG + 3) / 4, 256, 0, stream>>>(readout, post_w, post_b, (float*)d_out);
}

// Round 5
// 587.231 us; speedup vs baseline: 2.0410x; 1.0529x over previous
//
#include <hip/hip_runtime.h>
#include <hip/hip_fp16.h>

#define NN 100000
#define NE 1600000
#define FIN 128
#define HD 64
#define CO 40
#define NG 2048
#define NBLK1 98   // ceil(100000/1024)

// ---------------- histogram of dst (in-degree) ----------------
__global__ __launch_bounds__(256) void hist_kernel(const int* __restrict__ dst, int* __restrict__ degi) {
    int e = blockIdx.x * 256 + threadIdx.x;
    if (e < NE) atomicAdd(&degi[dst[e]], 1);
}

// ---------------- scan stage 1: per-block (1024 elems) exclusive scan ----------------
__global__ __launch_bounds__(256) void scan1_kernel(const int* __restrict__ degi,
                                                    int* __restrict__ offs,
                                                    int* __restrict__ bsums) {
    __shared__ int s[256];
    int t = threadIdx.x;
    int base = blockIdx.x * 1024 + t * 4;
    int v0 = 0, v1 = 0, v2 = 0, v3 = 0;
    if (base + 0 < NN) v0 = degi[base + 0];
    if (base + 1 < NN) v1 = degi[base + 1];
    if (base + 2 < NN) v2 = degi[base + 2];
    if (base + 3 < NN) v3 = degi[base + 3];
    int sum = v0 + v1 + v2 + v3;
    s[t] = sum;
    __syncthreads();
    for (int off = 1; off < 256; off <<= 1) {
        int x = (t >= off) ? s[t - off] : 0;
        __syncthreads();
        s[t] += x;
        __syncthreads();
    }
    int excl = s[t] - sum;
    if (t == 255) bsums[blockIdx.x] = s[255];
    int run = excl;
    if (base + 0 < NN) { offs[base + 0] = run; run += v0; }
    if (base + 1 < NN) { offs[base + 1] = run; run += v1; }
    if (base + 2 < NN) { offs[base + 2] = run; run += v2; }
    if (base + 3 < NN) { offs[base + 3] = run; run += v3; }
}

// ---------------- scan stage 2: scan the 98 block sums (inclusive) ----------------
__global__ __launch_bounds__(128) void scan2_kernel(int* __restrict__ bsums) {
    __shared__ int s[128];
    int t = threadIdx.x;
    s[t] = (t < NBLK1) ? bsums[t] : 0;
    __syncthreads();
    for (int off = 1; off < 128; off <<= 1) {
        int x = (t >= off) ? s[t - off] : 0;
        __syncthreads();
        s[t] += x;
        __syncthreads();
    }
    if (t < NBLK1) bsums[t] = s[t];
}

// ---------------- scan stage 3: add block prefix; emit cursor copy + deg_isqrt ----------------
__global__ __launch_bounds__(256) void scan3_kernel(const int* __restrict__ degi,
                                                    int* __restrict__ offs,
                                                    const int* __restrict__ bsums,
                                                    int* __restrict__ cursor,
                                                    float* __restrict__ di) {
    int i = blockIdx.x * 256 + threadIdx.x;
    if (i >= NN) return;
    int b = i >> 10;
    int add = (b > 0) ? bsums[b - 1] : 0;
    int o = offs[i] + add;
    offs[i] = o;
    cursor[i] = o;
    di[i] = rsqrtf((float)degi[i] + 1.0f);
}

// ---------------- build dst-sorted src list ----------------
__global__ __launch_bounds__(256) void build_kernel(const int* __restrict__ src,
                                                    const int* __restrict__ dst,
                                                    int* __restrict__ cursor,
                                                    int* __restrict__ ssrc) {
    int e = blockIdx.x * 256 + threadIdx.x;
    if (e >= NE) return;
    int d = dst[e];
    int pos = atomicAdd(&cursor[d], 1);
    ssrc[pos] = src[e];
}

// ---------------- W_eff = pre_w @ c1_w ; b_eff = pre_b @ c1_w ----------------
__global__ __launch_bounds__(256) void weff_kernel(const float* __restrict__ pre_w,
                                                   const float* __restrict__ pre_b,
                                                   const float* __restrict__ c1_w,
                                                   float* __restrict__ weff,
                                                   float* __restrict__ beff) {
    if (blockIdx.x < 32) {
        int o = blockIdx.x * 256 + threadIdx.x;  // o in [0, 8192)
        int r = o >> 6, c = o & 63;
        float acc = 0.0f;
#pragma unroll 8
        for (int k = 0; k < HD; k++) acc = fmaf(pre_w[r * HD + k], c1_w[k * HD + c], acc);
        weff[o] = acc;
    } else {
        int c = threadIdx.x;
        if (c < HD) {
            float acc = 0.0f;
#pragma unroll 8
            for (int k = 0; k < HD; k++) acc = fmaf(pre_b[k], c1_w[k * HD + c], acc);
            beff[c] = acc;
        }
    }
}

// ---------------- hws = half((x @ W_eff + b_eff) * di), persistent, 4 rows/wave ----------------
__global__ __launch_bounds__(256) void gemm1_kernel(const float* __restrict__ x,
                                                    const float* __restrict__ w,
                                                    const float* __restrict__ b,
                                                    const float* __restrict__ di,
                                                    __half* __restrict__ hws) {
    __shared__ float lw[FIN * HD];  // 32 KB
    for (int i = threadIdx.x; i < FIN * HD; i += 256) lw[i] = w[i];
    __syncthreads();
    int wv = threadIdx.x >> 6;
    int f = threadIdx.x & 63;
    float bf = b[f];
    for (int base = blockIdx.x * 16; base < NN; base += gridDim.x * 16) {
        int n0 = base + wv * 4;   // NN % 16 == 0 -> rows n0..n0+3 always valid
        const float4* x0 = (const float4*)(x + (size_t)(n0 + 0) * FIN);
        const float4* x1 = (const float4*)(x + (size_t)(n0 + 1) * FIN);
        const float4* x2 = (const float4*)(x + (size_t)(n0 + 2) * FIN);
        const float4* x3 = (const float4*)(x + (size_t)(n0 + 3) * FIN);
        float acc0 = bf, acc1 = bf, acc2 = bf, acc3 = bf;
#pragma unroll 4
        for (int k4 = 0; k4 < FIN / 4; k4++) {
            float4 a0 = x0[k4], a1 = x1[k4], a2 = x2[k4], a3 = x3[k4];
            float w0 = lw[(k4 * 4 + 0) * HD + f];
            float w1 = lw[(k4 * 4 + 1) * HD + f];
            float w2 = lw[(k4 * 4 + 2) * HD + f];
            float w3 = lw[(k4 * 4 + 3) * HD + f];
            acc0 = fmaf(a0.x, w0, acc0); acc1 = fmaf(a1.x, w0, acc1);
            acc2 = fmaf(a2.x, w0, acc2); acc3 = fmaf(a3.x, w0, acc3);
            acc0 = fmaf(a0.y, w1, acc0); acc1 = fmaf(a1.y, w1, acc1);
            acc2 = fmaf(a2.y, w1, acc2); acc3 = fmaf(a3.y, w1, acc3);
            acc0 = fmaf(a0.z, w2, acc0); acc1 = fmaf(a1.z, w2, acc1);
            acc2 = fmaf(a2.z, w2, acc2); acc3 = fmaf(a3.z, w2, acc3);
            acc0 = fmaf(a0.w, w3, acc0); acc1 = fmaf(a1.w, w3, acc1);
            acc2 = fmaf(a2.w, w3, acc2); acc3 = fmaf(a3.w, w3, acc3);
        }
        hws[(size_t)(n0 + 0) * HD + f] = __float2half_rn(acc0 * di[n0 + 0]);
        hws[(size_t)(n0 + 1) * HD + f] = __float2half_rn(acc1 * di[n0 + 1]);
        hws[(size_t)(n0 + 2) * HD + f] = __float2half_rn(acc2 * di[n0 + 2]);
        hws[(size_t)(n0 + 3) * HD + f] = __float2half_rn(acc3 * di[n0 + 3]);
    }
}

// ---------------- hws2 = half((h1 @ c2_w) * di), persistent, 4 rows/wave ----------------
__global__ __launch_bounds__(256) void conv_gemm(const float* __restrict__ hin,
                                                 const float* __restrict__ w,
                                                 const float* __restrict__ di,
                                                 __half* __restrict__ hws) {
    __shared__ float lw[HD * HD];  // 16 KB
    for (int i = threadIdx.x; i < HD * HD; i += 256) lw[i] = w[i];
    __syncthreads();
    int wv = threadIdx.x >> 6;
    int f = threadIdx.x & 63;
    for (int base = blockIdx.x * 16; base < NN; base += gridDim.x * 16) {
        int n0 = base + wv * 4;
        const float4* x0 = (const float4*)(hin + (size_t)(n0 + 0) * HD);
        const float4* x1 = (const float4*)(hin + (size_t)(n0 + 1) * HD);
        const float4* x2 = (const float4*)(hin + (size_t)(n0 + 2) * HD);
        const float4* x3 = (const float4*)(hin + (size_t)(n0 + 3) * HD);
        float acc0 = 0.0f, acc1 = 0.0f, acc2 = 0.0f, acc3 = 0.0f;
#pragma unroll 4
        for (int k4 = 0; k4 < HD / 4; k4++) {
            float4 a0 = x0[k4], a1 = x1[k4], a2 = x2[k4], a3 = x3[k4];
            float w0 = lw[(k4 * 4 + 0) * HD + f];
            float w1 = lw[(k4 * 4 + 1) * HD + f];
            float w2 = lw[(k4 * 4 + 2) * HD + f];
            float w3 = lw[(k4 * 4 + 3) * HD + f];
            acc0 = fmaf(a0.x, w0, acc0); acc1 = fmaf(a1.x, w0, acc1);
            acc2 = fmaf(a2.x, w0, acc2); acc3 = fmaf(a3.x, w0, acc3);
            acc0 = fmaf(a0.y, w1, acc0); acc1 = fmaf(a1.y, w1, acc1);
            acc2 = fmaf(a2.y, w1, acc2); acc3 = fmaf(a3.y, w1, acc3);
            acc0 = fmaf(a0.z, w2, acc0); acc1 = fmaf(a1.z, w2, acc1);
            acc2 = fmaf(a2.z, w2, acc2); acc3 = fmaf(a3.z, w2, acc3);
            acc0 = fmaf(a0.w, w3, acc0); acc1 = fmaf(a1.w, w3, acc1);
            acc2 = fmaf(a2.w, w3, acc2); acc3 = fmaf(a3.w, w3, acc3);
        }
        hws[(size_t)(n0 + 0) * HD + f] = __float2half_rn(acc0 * di[n0 + 0]);
        hws[(size_t)(n0 + 1) * HD + f] = __float2half_rn(acc1 * di[n0 + 1]);
        hws[(size_t)(n0 + 2) * HD + f] = __float2half_rn(acc2 * di[n0 + 2]);
        hws[(size_t)(n0 + 3) * HD + f] = __float2half_rn(acc3 * di[n0 + 3]);
    }
}

// =====================================================================
// Gather core (fp16 rows): wave per node, 8 lanes/row (16B each), 8 rows
// per shuffle round. All __shfl executed by all 64 lanes (bpermute rule).
// lane = rsub*8 + fp ; fp in [0,8) covers features fp*8..fp*8+7.
// Result: acc[0..7] valid in ALL lanes (features fp*8+t).
// =====================================================================
__device__ __forceinline__ void gather_half(const int* __restrict__ offs,
                                            const int* __restrict__ ssrc,
                                            const __half* __restrict__ hws,
                                            int node, int lane, int fp, int rsub,
                                            float acc[8]) {
    int beg = offs[node];
    int end = (node + 1 < NN) ? offs[node + 1] : NE;
    union U { float4 f4; __half2 h2[4]; } u;
#pragma unroll
    for (int t = 0; t < 8; t++) acc[t] = 0.0f;
    if (rsub == 0) {  // self-loop term counted once
        u.f4 = ((const float4*)(hws + (size_t)node * HD))[fp];
#pragma unroll
        for (int t = 0; t < 4; t++) {
            float2 p = __half22float2(u.h2[t]);
            acc[2 * t] += p.x; acc[2 * t + 1] += p.y;
        }
    }
    int i = beg;
    while (i < end) {
        int cnt = end - i;
        if (cnt > 64) cnt = 64;
        int sl = (lane < cnt) ? ssrc[i + lane] : 0;
        int j = 0;
        for (; j + 8 <= cnt; j += 8) {
            int s = __shfl(sl, j + rsub, 64);   // non-divergent
            u.f4 = ((const float4*)(hws + (size_t)s * HD))[fp];
#pragma unroll
            for (int t = 0; t < 4; t++) {
                float2 p = __half22float2(u.h2[t]);
                acc[2 * t] += p.x; acc[2 * t + 1] += p.y;
            }
        }
        if (j < cnt) {  // tail 1..7 rows
            int jr = j + rsub;
            int s = __shfl(sl, (jr < cnt) ? jr : 0, 64);  // all lanes execute
            if (jr < cnt) {
                u.f4 = ((const float4*)(hws + (size_t)s * HD))[fp];
#pragma unroll
                for (int t = 0; t < 4; t++) {
                    float2 p = __half22float2(u.h2[t]);
                    acc[2 * t] += p.x; acc[2 * t + 1] += p.y;
                }
            }
        }
        i += cnt;
    }
    // combine the 8 rsub groups (xor 8,16,32)
#pragma unroll
    for (int t = 0; t < 8; t++) {
        acc[t] += __shfl_xor(acc[t], 8, 64);
        acc[t] += __shfl_xor(acc[t], 16, 64);
        acc[t] += __shfl_xor(acc[t], 32, 64);
    }
}

// LN over the 8-features-per-lane layout; returns relu'd y[8].
__device__ __forceinline__ void ln8(float v[8], int fp,
                                    const float* __restrict__ g,
                                    const float* __restrict__ bb,
                                    float y[8]) {
    float su = 0.0f;
#pragma unroll
    for (int t = 0; t < 8; t++) su += v[t];
    su += __shfl_xor(su, 1, 64); su += __shfl_xor(su, 2, 64); su += __shfl_xor(su, 4, 64);
    float mu = su * (1.0f / HD);
    float q = 0.0f;
#pragma unroll
    for (int t = 0; t < 8; t++) { float d = v[t] - mu; q += d * d; }
    q += __shfl_xor(q, 1, 64); q += __shfl_xor(q, 2, 64); q += __shfl_xor(q, 4, 64);
    float rstd = rsqrtf(q * (1.0f / HD) + 1e-5f);
    float4 ga = ((const float4*)g)[fp * 2], gb = ((const float4*)g)[fp * 2 + 1];
    float4 ba = ((const float4*)bb)[fp * 2], bc = ((const float4*)bb)[fp * 2 + 1];
    const float* gg = &ga.x;  // consecutive float4 pair as array
    float gv[8] = {ga.x, ga.y, ga.z, ga.w, gb.x, gb.y, gb.z, gb.w};
    float bv[8] = {ba.x, ba.y, ba.z, ba.w, bc.x, bc.y, bc.z, bc.w};
    (void)gg;
#pragma unroll
    for (int t = 0; t < 8; t++) y[t] = fmaxf((v[t] - mu) * rstd * gv[t] + bv[t], 0.0f);
}

// ---------------- layer-1 gather + bias + LN + ReLU -> h1 (f32) ----------------
__global__ __launch_bounds__(256) void gather_ln(const int* __restrict__ offs,
                                                 const int* __restrict__ ssrc,
                                                 const float* __restrict__ di,
                                                 const __half* __restrict__ hws,
                                                 const float* __restrict__ cb,
                                                 const float* __restrict__ g,
                                                 const float* __restrict__ bb,
                                                 float* __restrict__ out) {
    int wv = threadIdx.x >> 6;
    int lane = threadIdx.x & 63;
    int fp = lane & 7, rsub = lane >> 3;
    int node = blockIdx.x * 4 + wv;      // NN % 4 == 0
    float acc[8];
    gather_half(offs, ssrc, hws, node, lane, fp, rsub, acc);
    float dn = di[node];
    float4 ca = ((const float4*)cb)[fp * 2], cc = ((const float4*)cb)[fp * 2 + 1];
    float cv[8] = {ca.x, ca.y, ca.z, ca.w, cc.x, cc.y, cc.z, cc.w};
    float v[8], y[8];
#pragma unroll
    for (int t = 0; t < 8; t++) v[t] = acc[t] * dn + cv[t];
    ln8(v, fp, g, bb, y);
    if (rsub == 0) {
        float4 o0 = {y[0], y[1], y[2], y[3]};
        float4 o1 = {y[4], y[5], y[6], y[7]};
        float* row = out + (size_t)node * HD + fp * 8;
        ((float4*)row)[0] = o0;
        ((float4*)row)[1] = o1;
    }
}

// ---------------- layer-2 gather + LN + ReLU + skip + pooled scatter ----------------
__global__ __launch_bounds__(256) void gather_ln_pool(const int* __restrict__ offs,
                                                      const int* __restrict__ ssrc,
                                                      const float* __restrict__ di,
                                                      const __half* __restrict__ hws,
                                                      const float* __restrict__ cb,
                                                      const float* __restrict__ g,
                                                      const float* __restrict__ bb,
                                                      const float* __restrict__ h1,
                                                      const int* __restrict__ batch,
                                                      float* __restrict__ readout) {
    __shared__ float ls[4][HD];
    __shared__ int lb[4];
    int wv = threadIdx.x >> 6;
    int lane = threadIdx.x & 63;
    int fp = lane & 7, rsub = lane >> 3;
    int node = blockIdx.x * 4 + wv;
    float acc[8];
    gather_half(offs, ssrc, hws, node, lane, fp, rsub, acc);
    float dn = di[node];
    float4 ca = ((const float4*)cb)[fp * 2], cc = ((const float4*)cb)[fp * 2 + 1];
    float cv[8] = {ca.x, ca.y, ca.z, ca.w, cc.x, cc.y, cc.z, cc.w};
    float v[8], y[8];
#pragma unroll
    for (int t = 0; t < 8; t++) v[t] = acc[t] * dn + cv[t];
    ln8(v, fp, g, bb, y);
    if (rsub == 0) {
        const float* h1row = h1 + (size_t)node * HD + fp * 8;
        float4 h0 = ((const float4*)h1row)[0];
        float4 h1v = ((const float4*)h1row)[1];
        float4 s0 = {y[0] + h0.x, y[1] + h0.y, y[2] + h0.z, y[3] + h0.w};
        float4 s1 = {y[4] + h1v.x, y[5] + h1v.y, y[6] + h1v.z, y[7] + h1v.w};
        float* lrow = &ls[wv][fp * 8];
        ((float4*)lrow)[0] = s0;
        ((float4*)lrow)[1] = s1;
    }
    if (lane == 0) lb[wv] = batch[node];
    __syncthreads();
    int f = lane;
    bool same = (lb[0] == lb[1]) && (lb[1] == lb[2]) && (lb[2] == lb[3]);
    if (same) {
        if (wv == 0) {
            float s4 = ls[0][f] + ls[1][f] + ls[2][f] + ls[3][f];
            atomicAdd(&readout[(size_t)lb[0] * HD + f], s4);
        }
    } else {
        atomicAdd(&readout[(size_t)lb[wv] * HD + f], ls[wv][f]);
    }
}

// ---------------- final: out = readout @ post_w + post_b  [G,64]@[64,40] ----------------
__global__ __launch_bounds__(256) void out_gemm(const float* __restrict__ r,
                                                const float* __restrict__ w,
                                                const float* __restrict__ b,
                                                float* __restrict__ out) {
    __shared__ float lw[HD * CO];
    for (int i = threadIdx.x; i < HD * CO; i += 256) lw[i] = w[i];
    __syncthreads();
    int grp = blockIdx.x * 4 + (threadIdx.x >> 6);
    int c = threadIdx.x & 63;
    if (grp >= NG || c >= CO) return;
    const float* rr = r + (size_t)grp * HD;
    float acc = b[c];
#pragma unroll 8
    for (int k = 0; k < HD; k++) acc = fmaf(rr[k], lw[k * CO + c], acc);
    out[(size_t)grp * CO + c] = acc;
}

extern "C" void kernel_launch(void* const* d_in, const int* in_sizes, int n_in,
                              void* d_out, int out_size, void* d_ws, size_t ws_size,
                              hipStream_t stream) {
    const float* x      = (const float*)d_in[0];
    const int*   ei     = (const int*)d_in[1];
    const int*   batch  = (const int*)d_in[2];
    const float* pre_w  = (const float*)d_in[3];
    const float* pre_b  = (const float*)d_in[4];
    const float* c1_w   = (const float*)d_in[5];
    const float* c1_b   = (const float*)d_in[6];
    const float* n1_g   = (const float*)d_in[7];
    const float* n1_b   = (const float*)d_in[8];
    const float* c2_w   = (const float*)d_in[9];
    const float* c2_b   = (const float*)d_in[10];
    const float* n2_g   = (const float*)d_in[11];
    const float* n2_b   = (const float*)d_in[12];
    const float* post_w = (const float*)d_in[13];
    const float* post_b = (const float*)d_in[14];

    const int* src = ei;
    const int* dst = ei + NE;

    char* p = (char*)d_ws;
    int*    degi    = (int*)p;                p += (size_t)NN * 4;
    int*    offs    = (int*)p;                p += (size_t)NN * 4;
    int*    cursor  = (int*)p;                p += (size_t)NN * 4;
    int*    bsums   = (int*)p;                p += 512;
    float*  di      = (float*)p;              p += (size_t)NN * 4;
    float*  weff    = (float*)p;              p += (size_t)FIN * HD * 4;
    float*  beff    = (float*)p;              p += 256;
    int*    ssrc    = (int*)p;                p += (size_t)NE * 4;
    float*  h1      = (float*)p;              p += (size_t)NN * HD * 4;
    float*  readout = (float*)p;              p += (size_t)NG * HD * 4;
    __half* hws     = (__half*)p;             p += (size_t)NN * HD * 2;

    hipMemsetAsync(degi, 0, (size_t)NN * 4, stream);
    hipMemsetAsync(readout, 0, (size_t)NG * HD * 4, stream);

    // CSR build (shared by both layers)
    hist_kernel<<<(NE + 255) / 256, 256, 0, stream>>>(dst, degi);
    scan1_kernel<<<NBLK1, 256, 0, stream>>>(degi, offs, bsums);
    scan2_kernel<<<1, 128, 0, stream>>>(bsums);
    scan3_kernel<<<(NN + 255) / 256, 256, 0, stream>>>(degi, offs, bsums, cursor, di);
    build_kernel<<<(NE + 255) / 256, 256, 0, stream>>>(src, dst, cursor, ssrc);

    // Folded pre-MLP weights
    weff_kernel<<<33, 256, 0, stream>>>(pre_w, pre_b, c1_w, weff, beff);

    // layer 1
    gemm1_kernel<<<1280, 256, 0, stream>>>(x, weff, beff, di, hws);
    gather_ln<<<NN / 4, 256, 0, stream>>>(offs, ssrc, di, hws, c1_b, n1_g, n1_b, h1);

    // layer 2
    conv_gemm<<<1280, 256, 0, stream>>>(h1, c2_w, di, hws);
    gather_ln_pool<<<NN / 4, 256, 0, stream>>>(offs, ssrc, di, hws, c2_b, n2_g, n2_b, h1, batch, readout);

    out_gemm<<<(NG + 3) / 4, 256, 0, stream>>>(readout, post_w, post_b, (float*)d_out);
}